// Round 2
// baseline (513.951 us; speedup 1.0000x reference)
//
#include <hip/hip_runtime.h>
#include <hip/hip_bf16.h>

#define T_STEPS 2048
#define BATCH 16
#define DIM 1024
#define NDIM 64
#define M_TOTAL (T_STEPS * BATCH)  // 32768
#define STRIDE (BATCH * NDIM)      // floats per timestep in Kp/Qp = 1024
#define CH 32                      // recurrence chunk (timesteps per LDS buffer)

typedef __attribute__((ext_vector_type(8))) short bf16x8;
typedef __attribute__((ext_vector_type(4))) float f32x4;
typedef __attribute__((ext_vector_type(2))) float f32x2;

#define NEG_LOG2E -1.44269504088896f

__device__ inline unsigned pk_bf(float lo, float hi) {
    __hip_bfloat162 h = __float22bfloat162_rn(float2{lo, hi});
    return *(unsigned*)&h;  // v_cvt_pk_bf16_f32
}

template <int CTRL>
__device__ inline float dpp_add(float x) {
    int v = __builtin_amdgcn_update_dpp(0, __float_as_int(x), CTRL, 0xF, 0xF, true);
    return x + __int_as_float(v);
}
// full sum across contiguous 16-lane rows (result in all 16 lanes)
__device__ inline float red16(float x) {
    x = dpp_add<0xB1>(x);   // quad_perm xor1
    x = dpp_add<0x4E>(x);   // quad_perm xor2
    x = dpp_add<0x141>(x);  // row_half_mirror (xor4)
    x = dpp_add<0x140>(x);  // row_mirror (xor8)
    return x;
}
// two independent 16-lane reductions, stage-interleaved so their DPP chains overlap
__device__ inline void red16x2(float& a, float& b) {
    a = dpp_add<0xB1>(a);  b = dpp_add<0xB1>(b);
    a = dpp_add<0x4E>(a);  b = dpp_add<0x4E>(b);
    a = dpp_add<0x141>(a); b = dpp_add<0x141>(b);
    a = dpp_add<0x140>(a); b = dpp_add<0x140>(b);
}
__device__ inline float dot4(f32x4 a, f32x4 b) {
    f32x2 t = a.lo * b.lo;
    t = a.hi * b.hi + t;
    return t.x + t.y;
}

#define AS1 __attribute__((address_space(1)))
#define AS3 __attribute__((address_space(3)))
__device__ inline void gl_lds16(const float* g, float* l) {
    __builtin_amdgcn_global_load_lds((const AS1 unsigned*)g, (AS3 unsigned*)l, 16, 0, 0);
}
__device__ inline void gl_lds16s(const unsigned short* g, unsigned short* l) {
    __builtin_amdgcn_global_load_lds((const AS1 unsigned*)g, (AS3 unsigned*)l, 16, 0, 0);
}
__device__ inline void gl_lds4(const float* g, float* l) {
    __builtin_amdgcn_global_load_lds((const AS1 unsigned*)g, (AS3 unsigned*)l, 4, 0, 0);
}
#define WAIT_VM0 do { __builtin_amdgcn_s_waitcnt(0x0F70); asm volatile("" ::: "memory"); } while (0)

// ---------------- W prepack: fp32 -> bf16, row order [K, Q, V, A] ----------------
__global__ __launch_bounds__(256) void pack_w(
    const float* __restrict__ Wk, const float* __restrict__ Wq,
    const float* __restrict__ Wv, const float* __restrict__ Wa,
    unsigned short* __restrict__ Wb) {
    int n = blockIdx.x;  // 0..255
    int sel = n >> 6;
    const float* W = (sel == 0) ? Wk : (sel == 1) ? Wq : (sel == 2) ? Wv : Wa;
    int k4 = threadIdx.x * 4;
    float4 f = *(const float4*)(W + (size_t)(n & 63) * DIM + k4);
    uint2 u;
    u.x = pk_bf(f.x, f.y);
    u.y = pk_bf(f.z, f.w);
    *(uint2*)(Wb + (size_t)n * DIM + k4) = u;
}

// ---------------- projection: m97-style 128x128 tile, global_load_lds staging ----------------
__global__ __launch_bounds__(256, 2) void proj_kernel(
    const float* __restrict__ x, const unsigned short* __restrict__ Wb,
    const float* __restrict__ ba, float* __restrict__ Kp, float* __restrict__ Qp,
    float* __restrict__ VAi) {
    __shared__ float sA[128 * 64];            // 32 KB fp32
    __shared__ unsigned short sB[128 * 64];   // 16 KB bf16

    const int m0 = blockIdx.x * 128;
    const int ntile = blockIdx.y;
    const int tid = threadIdx.x;
    const int wv = tid >> 6, lane = tid & 63, lrow = lane & 15, quad = lane >> 4;
    const int wm = wv & 1, wn = wv >> 1;   // wave = (m-half, n-half) of 128x128 tile

    f32x4 acc[4][4];
#pragma unroll
    for (int a = 0; a < 4; a++)
#pragma unroll
        for (int b = 0; b < 4; b++) acc[a][b] = (f32x4)(0.f);

    const float* xg = x + (size_t)(m0 + (tid >> 4)) * DIM + (tid & 15) * 4;
    const unsigned short* wg = Wb + (size_t)(ntile * 128 + (tid >> 3)) * DIM + (tid & 7) * 8;

    for (int it = 0; it < 16; ++it) {
        const int k0 = it * 64;
        __syncthreads();  // previous iteration's frag reads done
#pragma unroll
        for (int j = 0; j < 8; ++j)  // A: 128x64 fp32 = 32 KB
            gl_lds16(xg + (size_t)(16 * j) * DIM + k0, &sA[(tid + 256 * j) * 4]);
#pragma unroll
        for (int j = 0; j < 4; ++j)  // B: 128x64 bf16 = 16 KB
            gl_lds16s(wg + (size_t)(32 * j) * DIM + k0, &sB[(tid + 256 * j) * 8]);
        WAIT_VM0;
        __syncthreads();

#pragma unroll
        for (int ks = 0; ks < 2; ++ks) {
            bf16x8 af[4];
#pragma unroll
            for (int mt = 0; mt < 4; ++mt) {
                const float* pa = &sA[(wm * 64 + mt * 16 + lrow) * 64 + ks * 32 + quad * 8];
                float4 lo = ((const float4*)pa)[0], hi = ((const float4*)pa)[1];
                unsigned pk[4] = {pk_bf(lo.x, lo.y), pk_bf(lo.z, lo.w),
                                  pk_bf(hi.x, hi.y), pk_bf(hi.z, hi.w)};
                af[mt] = *(bf16x8*)pk;
            }
#pragma unroll
            for (int nt = 0; nt < 4; ++nt) {
                bf16x8 bfr = *(const bf16x8*)&sB[(wn * 64 + nt * 16 + lrow) * 64 + ks * 32 + quad * 8];
#pragma unroll
                for (int mt = 0; mt < 4; ++mt)
                    acc[mt][nt] = __builtin_amdgcn_mfma_f32_16x16x32_bf16(af[mt], bfr, acc[mt][nt], 0, 0, 0);
            }
        }
    }

    // epilogue: C/D layout col = lane&15, row = quad*4 + reg  [m89-verified]
    const int g2 = ntile * 2 + wn;  // 0=K 1=Q 2=V 3=A
    float bav[4];
    if (g2 == 3) {
#pragma unroll
        for (int nt = 0; nt < 4; ++nt) bav[nt] = ba[nt * 16 + lrow];
    }
#pragma unroll
    for (int mt = 0; mt < 4; ++mt)
#pragma unroll
        for (int nt = 0; nt < 4; ++nt) {
            int col = nt * 16 + lrow;
#pragma unroll
            for (int reg = 0; reg < 4; ++reg) {
                int m = m0 + wm * 64 + mt * 16 + quad * 4 + reg;
                float vvv = acc[mt][nt][reg];
                if (g2 == 0) Kp[(size_t)m * 64 + col] = vvv;
                else if (g2 == 1) Qp[(size_t)m * 64 + col] = vvv;
                else if (g2 == 2) VAi[(size_t)m * 128 + col * 2] = vvv;
                else VAi[(size_t)m * 128 + col * 2 + 1] = NEG_LOG2E * (vvv + bav[nt]);
            }
        }
}

// ---------------- kq[m] = K[m,:].Q[m,:]   kk[m] = K[m,:].K[m+B,:]  (k_t . k_{t+1}) ----------------
__global__ __launch_bounds__(256) void kq_kernel(
    const float* __restrict__ Kp, const float* __restrict__ Qp,
    float* __restrict__ kq, float* __restrict__ kk) {
    int m = blockIdx.x * 16 + (threadIdx.x >> 4);
    int c = threadIdx.x & 15;
    float4 k = *(const float4*)(Kp + (size_t)m * 64 + c * 4);
    float4 q = *(const float4*)(Qp + (size_t)m * 64 + c * 4);
    float4 kn = {0.f, 0.f, 0.f, 0.f};
    if (m + BATCH < M_TOTAL) kn = *(const float4*)(Kp + (size_t)(m + BATCH) * 64 + c * 4);
    float pq = k.x * q.x + k.y * q.y + k.z * q.z + k.w * q.w;
    float pk = k.x * kn.x + k.y * kn.y + k.z * kn.z + k.w * kn.w;
    pq = red16(pq);
    pk = red16(pk);
    if (c == 0) { kq[m] = pq; kk[m] = pk; }
}

// ---------------- recurrence ----------------
// grid (16 row-groups, 16 batches) x 64; lane = r*16+c; row i = g*4+r, cols c*4..+3
//
// Software-pipelined so that every value consumed at step t was produced at step t-1
// or earlier (in-order wave: any in-line dependent chain stalls issue):
//   - alpha_t = rcp(1 + e_t) with e_t = exp2(z_t) produced at step t-1 (right after rk_t)
//   - red16s at step t compute rq/ck for step t+1 from s_t (their DPP latency percolates
//     under step t+1's alpha/silu issue)
//   - the output silu of o_{t-1} is evaluated at step t (operands a full step old)
// Loop-carried chain: rcp -> fma(rk) -> fma(z) -> exp2 -> add  (~50 cy/step floor).
__global__ __launch_bounds__(64, 1) void recur_kernel(
    const float* __restrict__ Kp, const float* __restrict__ Qp,
    const float* __restrict__ VAi, const float* __restrict__ KQp,
    const float* __restrict__ KKp,
    const float* __restrict__ S0, const float* __restrict__ d_alpha,
    float* __restrict__ out, float* __restrict__ Sout) {
    __shared__ float Kl[2][CH][64];   // 16 KB
    __shared__ float Ql[2][CH][64];   // 16 KB
    __shared__ float VAl[2][CH][8];   // 2 KB: [t] = v0,a0,v1,a1,v2,a2,v3,a3 (rows g*4..+3)
    __shared__ float KQl[2][64];      // 0.5 KB (only [0..31] used)
    __shared__ float KKl[2][64];      // 0.5 KB
    __shared__ float Ol[CH][4];       // per-chunk output staging

    int b = blockIdx.y, g = blockIdx.x, lane = threadIdx.x;
    int r = lane >> 4, c = lane & 15, i = g * 4 + r, c4 = c * 4;

    f32x4 sv = *(const f32x4*)(S0 + ((size_t)b * NDIM + i) * NDIM + c4);
    float da2 = d_alpha[i] * NEG_LOG2E;  // alpha logit pre-scaled for exp2 form

    const float* Kbase = Kp + (size_t)b * NDIM + (size_t)(lane >> 4) * STRIDE + (lane & 15) * 4;
    const float* Qbase = Qp + (size_t)b * NDIM + (size_t)(lane >> 4) * STRIDE + (lane & 15) * 4;
    const float* VAbase = VAi + (size_t)b * 128 + g * 8 + (lane & 1) * 4 + (size_t)(lane >> 1) * 2048;
    const float* KQbase = KQp + b + (size_t)(lane & 31) * BATCH;
    const float* KKbase = KKp + b + (size_t)(lane & 31) * BATCH;

    auto load_chunk = [&](int t0, int buf) {
#pragma unroll
        for (int j = 0; j < 8; ++j) {
            gl_lds16(Kbase + (size_t)(t0 + j * 4) * STRIDE, &Kl[buf][j * 4][0]);
            gl_lds16(Qbase + (size_t)(t0 + j * 4) * STRIDE, &Ql[buf][j * 4][0]);
        }
        gl_lds16(VAbase + (size_t)t0 * 2048, &VAl[buf][0][0]);
        gl_lds4(KQbase + (size_t)t0 * BATCH, &KQl[buf][0]);
        gl_lds4(KKbase + (size_t)t0 * BATCH, &KKl[buf][0]);
    };

    load_chunk(0, 0);
    WAIT_VM0;

    // ---- register slot pipelines (all indices fold after unroll) ----
    // kreg[v&3] holds k_v; loaded at iter v-4, matvec-consumed at v-2, outer-consumed at v
    // qreg/va2/kq2/kk2 slot (u&1) loaded at iter u with index u+2, consumed at iter u+1
    f32x4 kreg[4], qreg[2];
    f32x2 va2[2];
    float kq2[2], kk2[2];
    float ee, ckm, rqm, vkq, vkk, v_cur, o_prev = 0.f;

    {   // prologue: fill pipelines + compute step-0 inputs from S0
        const float* K0 = &Kl[0][0][0];
        const float* Q0 = &Ql[0][0][0];
        kreg[0] = *(const f32x4*)(K0 + 0 * 64 + c4);
        kreg[1] = *(const f32x4*)(K0 + 1 * 64 + c4);
        kreg[2] = *(const f32x4*)(K0 + 2 * 64 + c4);
        kreg[3] = *(const f32x4*)(K0 + 3 * 64 + c4);
        qreg[1] = *(const f32x4*)(Q0 + 1 * 64 + c4);
        va2[1] = *(const f32x2*)&VAl[0][1][r * 2];
        kq2[1] = KQl[0][1];
        kk2[1] = KKl[0][1];
        f32x4 q0 = *(const f32x4*)(Q0 + 0 * 64 + c4);
        f32x2 va0 = *(const f32x2*)&VAl[0][0][r * 2];
        float kq0 = KQl[0][0], kk0 = KKl[0][0];

        float rk0 = dot4(kreg[0], sv);   // S0 . k_0
        float rq0 = dot4(q0, sv);        // S0 . q_0
        float ck0 = dot4(kreg[1], sv);   // S0 . k_1
        red16x2(rk0, rq0);
        ck0 = red16(ck0);

        ee = __builtin_amdgcn_exp2f(fmaf(da2, rk0, va0.y));
        vkq = va0.x * kq0;
        vkk = va0.x * kk0;
        rqm = rq0 - vkq;
        ckm = ck0 - vkk;
        v_cur = va0.x;
    }

#define STEP(tl) do {                                                          \
    const int cs_ = ((tl) + 1) & 1, ls_ = (tl) & 1;                            \
    f32x4 qv_ = qreg[cs_];                                                     \
    f32x2 vax_ = va2[cs_];                                                     \
    float kq1_ = kq2[cs_], kk1_ = kk2[cs_];                                    \
    f32x4 kv_ = kreg[(tl) & 3];                                                \
    f32x4 kmv_ = kreg[((tl) + 2) & 3];                                         \
    {   const int i2_ = (tl) + 2;                                              \
        const float* Qs_ = (i2_ < CH) ? Qc : Qn;                               \
        const float* Vs_ = (i2_ < CH) ? Vc : Vn;                               \
        const float* QKs_ = (i2_ < CH) ? QKc : QKn;                            \
        const float* KKs_ = (i2_ < CH) ? KKc : KKn;                            \
        const int m2_ = i2_ & (CH - 1);                                        \
        qreg[ls_] = *(const f32x4*)(Qs_ + m2_ * 64 + c4);                      \
        va2[ls_] = *(const f32x2*)(Vs_ + m2_ * 8 + r * 2);                     \
        kq2[ls_] = QKs_[m2_];                                                  \
        kk2[ls_] = KKs_[m2_];                                                  \
        const int i4_ = (tl) + 4;                                              \
        const float* Ks_ = (i4_ < CH) ? Kc : Kn_;                              \
        kreg[(tl) & 3] = *(const f32x4*)(Ks_ + (i4_ & (CH - 1)) * 64 + c4); }  \
    float alpha_ = __builtin_amdgcn_rcpf(1.f + ee);                            \
    f32x4 w_ = v_cur * kv_;                                                    \
    f32x4 dd_ = sv - w_;                                                       \
    float rk1_ = fmaf(alpha_, ckm, vkk);                                       \
    sv = w_ + alpha_ * dd_;                                                    \
    float z_ = fmaf(da2, rk1_, vax_.y);                                        \
    float o_ = fmaf(alpha_, rqm, vkq);                                         \
    ee = __builtin_amdgcn_exp2f(z_);                                           \
    f32x2 tq_ = qv_.lo * sv.lo;  tq_ = qv_.hi * sv.hi + tq_;                   \
    f32x2 tk_ = kmv_.lo * sv.lo; tk_ = kmv_.hi * sv.hi + tk_;                  \
    float pq_ = tq_.x + tq_.y, pk_ = tk_.x + tk_.y;                            \
    red16x2(pq_, pk_);                                                         \
    float vkqn_ = vax_.x * kq1_, vkkn_ = vax_.x * kk1_;                        \
    rqm = pq_ - vkqn_;                                                         \
    ckm = pk_ - vkkn_;                                                         \
    vkq = vkqn_; vkk = vkkn_;                                                  \
    if ((tl) > 0) {                                                            \
        float eo_ = __builtin_amdgcn_exp2f(o_prev * NEG_LOG2E);                \
        float so_ = __builtin_amdgcn_rcpf(1.f + eo_);                          \
        float ov_ = o_prev * o_prev * so_;                                     \
        if (c == 0) Ol[(tl) - 1][r] = ov_; }                                   \
    o_prev = o_;                                                               \
    v_cur = vax_.x;                                                            \
} while (0)

    for (int j = 0; j < T_STEPS / CH; ++j) {
        const int cb = j & 1, nb = cb ^ 1;
        if (j + 1 < T_STEPS / CH) load_chunk((j + 1) * CH, nb);

        const float* Kc = &Kl[cb][0][0];
        const float* Kn_ = &Kl[nb][0][0];
        const float* Qc = &Ql[cb][0][0];
        const float* Qn = &Ql[nb][0][0];
        const float* Vc = &VAl[cb][0][0];
        const float* Vn = &VAl[nb][0][0];
        const float* QKc = &KQl[cb][0];
        const float* QKn = &KQl[nb][0];
        const float* KKc = &KKl[cb][0];
        const float* KKn = &KKl[nb][0];

#pragma unroll
        for (int tl = 0; tl < 28; ++tl) STEP(tl);
        WAIT_VM0;  // next-chunk staging (issued 28 steps ago) + old stores retired
#pragma unroll
        for (int tl = 28; tl < 32; ++tl) STEP(tl);

        {   // chunk epilogue: silu of the last o, then dump outputs
            float eo = __builtin_amdgcn_exp2f(o_prev * NEG_LOG2E);
            float so = __builtin_amdgcn_rcpf(1.f + eo);
            float ov = o_prev * o_prev * so;
            if (c == 0) Ol[CH - 1][r] = ov;
        }
        if (lane < 32) {  // lane = local t, 4 rows as float4
            float4 t4 = *(const float4*)&Ol[lane][0];
            *(float4*)(out + ((size_t)(j * CH + lane) * BATCH + b) * NDIM + g * 4) = t4;
        }
    }
#undef STEP

    float* so_ = Sout + ((size_t)b * NDIM + i) * NDIM + c4;
    *(float4*)so_ = float4{sv.x, sv.y, sv.z, sv.w};
}

extern "C" void kernel_launch(void* const* d_in, const int* in_sizes, int n_in,
                              void* d_out, int out_size, void* d_ws, size_t ws_size,
                              hipStream_t stream) {
    const float* x  = (const float*)d_in[0];
    const float* S0 = (const float*)d_in[1];
    const float* Wk = (const float*)d_in[2];
    const float* Wv = (const float*)d_in[3];
    const float* Wq = (const float*)d_in[4];
    const float* Wa = (const float*)d_in[5];
    const float* da = (const float*)d_in[6];
    const float* ba = (const float*)d_in[7];

    float* out = (float*)d_out;
    float* Sout = out + (size_t)T_STEPS * BATCH * NDIM;

    const size_t per = (size_t)M_TOTAL * NDIM;
    float* Kp  = (float*)d_ws;           // per floats
    float* Qp  = Kp + per;               // per
    float* VAi = Qp + per;               // 2*per (v,a interleaved per row)
    float* kq  = VAi + 2 * per;          // M_TOTAL
    float* kk  = kq + M_TOTAL;           // M_TOTAL (k_t . k_{t+1})
    unsigned short* Wb = (unsigned short*)(kk + M_TOTAL);  // 512 KB bf16

    pack_w<<<dim3(256), dim3(256), 0, stream>>>(Wk, Wq, Wv, Wa, Wb);
    proj_kernel<<<dim3(M_TOTAL / 128, 2), dim3(256), 0, stream>>>(x, Wb, ba, Kp, Qp, VAi);
    kq_kernel<<<dim3(M_TOTAL / 16), dim3(256), 0, stream>>>(Kp, Qp, kq, kk);
    recur_kernel<<<dim3(16, BATCH), dim3(64), 0, stream>>>(Kp, Qp, VAi, kq, kk, S0, da, out, Sout);
}

// Round 3
// 507.473 us; speedup vs baseline: 1.0128x; 1.0128x over previous
//
#include <hip/hip_runtime.h>
#include <hip/hip_bf16.h>

#define T_STEPS 2048
#define BATCH 16
#define DIM 1024
#define NDIM 64
#define M_TOTAL (T_STEPS * BATCH)  // 32768
#define STRIDE (BATCH * NDIM)      // floats per timestep in Kp/Qp = 1024
#define CH 32                      // recurrence chunk (timesteps per LDS buffer)

typedef __attribute__((ext_vector_type(8))) short bf16x8;
typedef __attribute__((ext_vector_type(4))) float f32x4;
typedef __attribute__((ext_vector_type(2))) float f32x2;

#define NEG_LOG2E -1.44269504088896f

__device__ inline unsigned pk_bf(float lo, float hi) {
    __hip_bfloat162 h = __float22bfloat162_rn(float2{lo, hi});
    return *(unsigned*)&h;  // v_cvt_pk_bf16_f32
}

template <int CTRL>
__device__ inline float dpp_add(float x) {
    int v = __builtin_amdgcn_update_dpp(0, __float_as_int(x), CTRL, 0xF, 0xF, true);
    return x + __int_as_float(v);
}
// full sum across contiguous 16-lane rows (result in all 16 lanes)
__device__ inline float red16(float x) {
    x = dpp_add<0xB1>(x);   // quad_perm xor1
    x = dpp_add<0x4E>(x);   // quad_perm xor2
    x = dpp_add<0x141>(x);  // row_half_mirror (xor4)
    x = dpp_add<0x140>(x);  // row_mirror (xor8)
    return x;
}
// two independent 16-lane reductions, stage-interleaved so their DPP chains overlap
__device__ inline void red16x2(float& a, float& b) {
    a = dpp_add<0xB1>(a);  b = dpp_add<0xB1>(b);
    a = dpp_add<0x4E>(a);  b = dpp_add<0x4E>(b);
    a = dpp_add<0x141>(a); b = dpp_add<0x141>(b);
    a = dpp_add<0x140>(a); b = dpp_add<0x140>(b);
}

#define AS1 __attribute__((address_space(1)))
#define AS3 __attribute__((address_space(3)))
__device__ inline void gl_lds16(const float* g, float* l) {
    __builtin_amdgcn_global_load_lds((const AS1 unsigned*)g, (AS3 unsigned*)l, 16, 0, 0);
}
__device__ inline void gl_lds16s(const unsigned short* g, unsigned short* l) {
    __builtin_amdgcn_global_load_lds((const AS1 unsigned*)g, (AS3 unsigned*)l, 16, 0, 0);
}
__device__ inline void gl_lds4(const float* g, float* l) {
    __builtin_amdgcn_global_load_lds((const AS1 unsigned*)g, (AS3 unsigned*)l, 4, 0, 0);
}
#define WAIT_VM0 do { __builtin_amdgcn_s_waitcnt(0x0F70); asm volatile("" ::: "memory"); } while (0)

// ---------------- W prepack: fp32 -> bf16, row order [K, Q, V, A] ----------------
__global__ __launch_bounds__(256) void pack_w(
    const float* __restrict__ Wk, const float* __restrict__ Wq,
    const float* __restrict__ Wv, const float* __restrict__ Wa,
    unsigned short* __restrict__ Wb) {
    int n = blockIdx.x;  // 0..255
    int sel = n >> 6;
    const float* W = (sel == 0) ? Wk : (sel == 1) ? Wq : (sel == 2) ? Wv : Wa;
    int k4 = threadIdx.x * 4;
    float4 f = *(const float4*)(W + (size_t)(n & 63) * DIM + k4);
    uint2 u;
    u.x = pk_bf(f.x, f.y);
    u.y = pk_bf(f.z, f.w);
    *(uint2*)(Wb + (size_t)n * DIM + k4) = u;
}

// ---------------- projection: m97-style 128x128 tile, global_load_lds staging ----------------
__global__ __launch_bounds__(256, 2) void proj_kernel(
    const float* __restrict__ x, const unsigned short* __restrict__ Wb,
    const float* __restrict__ ba, float* __restrict__ Kp, float* __restrict__ Qp,
    float* __restrict__ VAi) {
    __shared__ float sA[128 * 64];            // 32 KB fp32
    __shared__ unsigned short sB[128 * 64];   // 16 KB bf16

    const int m0 = blockIdx.x * 128;
    const int ntile = blockIdx.y;
    const int tid = threadIdx.x;
    const int wv = tid >> 6, lane = tid & 63, lrow = lane & 15, quad = lane >> 4;
    const int wm = wv & 1, wn = wv >> 1;   // wave = (m-half, n-half) of 128x128 tile

    f32x4 acc[4][4];
#pragma unroll
    for (int a = 0; a < 4; a++)
#pragma unroll
        for (int b = 0; b < 4; b++) acc[a][b] = (f32x4)(0.f);

    const float* xg = x + (size_t)(m0 + (tid >> 4)) * DIM + (tid & 15) * 4;
    const unsigned short* wg = Wb + (size_t)(ntile * 128 + (tid >> 3)) * DIM + (tid & 7) * 8;

    for (int it = 0; it < 16; ++it) {
        const int k0 = it * 64;
        __syncthreads();  // previous iteration's frag reads done
#pragma unroll
        for (int j = 0; j < 8; ++j)  // A: 128x64 fp32 = 32 KB
            gl_lds16(xg + (size_t)(16 * j) * DIM + k0, &sA[(tid + 256 * j) * 4]);
#pragma unroll
        for (int j = 0; j < 4; ++j)  // B: 128x64 bf16 = 16 KB
            gl_lds16s(wg + (size_t)(32 * j) * DIM + k0, &sB[(tid + 256 * j) * 8]);
        WAIT_VM0;
        __syncthreads();

#pragma unroll
        for (int ks = 0; ks < 2; ++ks) {
            bf16x8 af[4];
#pragma unroll
            for (int mt = 0; mt < 4; ++mt) {
                const float* pa = &sA[(wm * 64 + mt * 16 + lrow) * 64 + ks * 32 + quad * 8];
                float4 lo = ((const float4*)pa)[0], hi = ((const float4*)pa)[1];
                unsigned pk[4] = {pk_bf(lo.x, lo.y), pk_bf(lo.z, lo.w),
                                  pk_bf(hi.x, hi.y), pk_bf(hi.z, hi.w)};
                af[mt] = *(bf16x8*)pk;
            }
#pragma unroll
            for (int nt = 0; nt < 4; ++nt) {
                bf16x8 bfr = *(const bf16x8*)&sB[(wn * 64 + nt * 16 + lrow) * 64 + ks * 32 + quad * 8];
#pragma unroll
                for (int mt = 0; mt < 4; ++mt)
                    acc[mt][nt] = __builtin_amdgcn_mfma_f32_16x16x32_bf16(af[mt], bfr, acc[mt][nt], 0, 0, 0);
            }
        }
    }

    // epilogue: C/D layout col = lane&15, row = quad*4 + reg  [m89-verified]
    const int g2 = ntile * 2 + wn;  // 0=K 1=Q 2=V 3=A
    float bav[4];
    if (g2 == 3) {
#pragma unroll
        for (int nt = 0; nt < 4; ++nt) bav[nt] = ba[nt * 16 + lrow];
    }
#pragma unroll
    for (int mt = 0; mt < 4; ++mt)
#pragma unroll
        for (int nt = 0; nt < 4; ++nt) {
            int col = nt * 16 + lrow;
#pragma unroll
            for (int reg = 0; reg < 4; ++reg) {
                int m = m0 + wm * 64 + mt * 16 + quad * 4 + reg;
                float vvv = acc[mt][nt][reg];
                if (g2 == 0) Kp[(size_t)m * 64 + col] = vvv;
                else if (g2 == 1) Qp[(size_t)m * 64 + col] = vvv;
                else if (g2 == 2) VAi[(size_t)m * 128 + col * 2] = vvv;
                else VAi[(size_t)m * 128 + col * 2 + 1] = NEG_LOG2E * (vvv + bav[nt]);
            }
        }
}

// ---------------- kq[m] = K[m,:] . Q[m,:] ----------------
__global__ __launch_bounds__(256) void kq_kernel(
    const float* __restrict__ Kp, const float* __restrict__ Qp, float* __restrict__ kq) {
    int m = blockIdx.x * 16 + (threadIdx.x >> 4);
    int c = threadIdx.x & 15;
    float4 k = *(const float4*)(Kp + (size_t)m * 64 + c * 4);
    float4 q = *(const float4*)(Qp + (size_t)m * 64 + c * 4);
    float p = k.x * q.x + k.y * q.y + k.z * q.z + k.w * q.w;
    p = red16(p);
    if (c == 0) kq[m] = p;
}

// ---------------- elementwise silu epilogue: out = o*o*sigmoid(o) ----------------
__global__ __launch_bounds__(256) void silu_kernel(float* __restrict__ out) {
    size_t idx = ((size_t)blockIdx.x * 256 + threadIdx.x) * 4;
    f32x4 o = *(const f32x4*)(out + idx);
    f32x4 rr;
#pragma unroll
    for (int j = 0; j < 4; ++j) {
        float e = __builtin_amdgcn_exp2f(o[j] * NEG_LOG2E);
        rr[j] = o[j] * o[j] * __builtin_amdgcn_rcpf(1.f + e);
    }
    *(f32x4*)(out + idx) = rr;
}

// ---------------- recurrence ----------------
// grid (16 row-groups, 16 batches) x 64; lane = r*16+c; row i = g*4+r, cols c*4..+3
//
// THEORY (R3): all prior schedules plateaued at ~300 cy/step independent of dependency
// structure -> instruction-fetch bound (32-step fully-unrolled body = 14-20 KB walked
// every chunk, 1 wave/CU so I-miss latency is exposed). Fix: rolled 4-step body
// (~2 KB, L1I-resident), R0 dataflow (minimum instructions), silu moved to its own pass.
__global__ __launch_bounds__(64, 1) void recur_kernel(
    const float* __restrict__ Kp, const float* __restrict__ Qp,
    const float* __restrict__ VAi, const float* __restrict__ KQp,
    const float* __restrict__ S0, const float* __restrict__ d_alpha,
    float* __restrict__ out, float* __restrict__ Sout) {
    __shared__ float Kl[2][CH][64];   // 16 KB
    __shared__ float Ql[2][CH][64];   // 16 KB
    __shared__ float VAl[2][CH][8];   // 2 KB: [t] = v0,a0,v1,a1,v2,a2,v3,a3 (rows g*4..+3)
    __shared__ float KQl[2][64];      // 0.5 KB (only [0..31] used per buffer)
    __shared__ float Ol[CH][4];       // per-chunk output staging

    int b = blockIdx.y, g = blockIdx.x, lane = threadIdx.x;
    int r = lane >> 4, c = lane & 15, i = g * 4 + r, c4 = c * 4;

    float4 sv = *(const float4*)(S0 + ((size_t)b * NDIM + i) * NDIM + c4);
    f32x2 s01 = {sv.x, sv.y}, s23 = {sv.z, sv.w};
    float da2 = d_alpha[i] * NEG_LOG2E;  // alpha logit pre-scaled for exp2 form

    const float* Kbase = Kp + (size_t)b * NDIM + (size_t)(lane >> 4) * STRIDE + (lane & 15) * 4;
    const float* Qbase = Qp + (size_t)b * NDIM + (size_t)(lane >> 4) * STRIDE + (lane & 15) * 4;
    const float* VAbase = VAi + (size_t)b * 128 + g * 8 + (lane & 1) * 4 + (size_t)(lane >> 1) * 2048;
    const float* KQbase = KQp + b + (size_t)(lane & 31) * BATCH;

    auto load_chunk = [&](int t0, int buf) {
#pragma unroll
        for (int j = 0; j < 8; ++j) {
            gl_lds16(Kbase + (size_t)(t0 + j * 4) * STRIDE, &Kl[buf][j * 4][0]);
            gl_lds16(Qbase + (size_t)(t0 + j * 4) * STRIDE, &Ql[buf][j * 4][0]);
        }
        gl_lds16(VAbase + (size_t)t0 * 2048, &VAl[buf][0][0]);
        gl_lds4(KQbase + (size_t)t0 * BATCH, &KQl[buf][0]);
    };

    load_chunk(0, 0);
    WAIT_VM0;

    // register slot pipeline: slot sl=t&1 holds (k,q,va,kq) for step t; at step t the
    // freed slot is refilled with index t+2. Dead loads at t=30,31 read in-block LDS
    // garbage (next buffer / neighboring arrays) and are overwritten by the preload.
    f32x2 k01[2], k23[2], q01[2], q23[2], va[2];
    float kqv[2];
    {
        const float* Kb0 = &Kl[0][0][0] + c4;
        const float* Qb0 = &Ql[0][0][0] + c4;
#pragma unroll
        for (int u = 0; u < 2; ++u) {
            f32x4 kk_ = *(const f32x4*)(Kb0 + u * 64);
            f32x4 qq_ = *(const f32x4*)(Qb0 + u * 64);
            k01[u] = kk_.lo; k23[u] = kk_.hi;
            q01[u] = qq_.lo; q23[u] = qq_.hi;
            va[u] = *(const f32x2*)&VAl[0][u][r * 2];
            kqv[u] = KQl[0][u];
        }
    }

#define STEP(u, sl) do {                                                        \
    f32x2 k0v = k01[sl], k1v = k23[sl], q0v = q01[sl], q1v = q23[sl];           \
    f32x2 vva = va[sl];                                                         \
    float kqs = kqv[sl];                                                        \
    f32x4 kk_ = *(const f32x4*)(Kt + (u + 2) * 64);                             \
    f32x4 qq_ = *(const f32x4*)(Qt + (u + 2) * 64);                             \
    k01[sl] = kk_.lo; k23[sl] = kk_.hi;                                         \
    q01[sl] = qq_.lo; q23[sl] = qq_.hi;                                         \
    va[sl] = *(const f32x2*)(Vt + (u + 2) * 8);                                 \
    kqv[sl] = Qk[t4 + u + 2];                                                   \
    f32x2 pk_ = k0v * s01; pk_ = k1v * s23 + pk_;                               \
    f32x2 pq_ = q0v * s01; pq_ = q1v * s23 + pq_;                               \
    float rk_ = pk_.x + pk_.y, rq_ = pq_.x + pq_.y;                             \
    red16x2(rk_, rq_);                                                          \
    float v_ = vva.x;                                                           \
    f32x2 w01 = v_ * k0v, w23 = v_ * k1v;                                       \
    f32x2 d01 = s01 - w01, d23 = s23 - w23;                                     \
    float alpha_ = __builtin_amdgcn_rcpf(                                       \
        1.f + __builtin_amdgcn_exp2f(fmaf(da2, rk_, vva.y)));                   \
    f32x2 a2 = {alpha_, alpha_};                                                \
    s01 = w01 + a2 * d01;                                                       \
    s23 = w23 + a2 * d23;                                                       \
    float vkq_ = v_ * kqs;                                                      \
    float o_ = fmaf(alpha_, rq_ - vkq_, vkq_);  /* S_t.q_t */                   \
    if (c == 0) Ol[t4 + u][r] = o_;                                             \
} while (0)

#pragma unroll 1
    for (int j = 0; j < T_STEPS / CH; ++j) {
        const int cb = j & 1, nb = cb ^ 1;
        if (j + 1 < T_STEPS / CH) load_chunk((j + 1) * CH, nb);

        const float* Kb = &Kl[cb][0][0] + c4;
        const float* Qb = &Ql[cb][0][0] + c4;
        const float* Vb = &VAl[cb][0][0] + r * 2;
        const float* Qk = &KQl[cb][0];

#pragma unroll 1
        for (int t4 = 0; t4 < CH; t4 += 4) {   // rolled: ~2 KB hot body, L1I-resident
            const float* Kt = Kb + t4 * 64;
            const float* Qt = Qb + t4 * 64;
            const float* Vt = Vb + t4 * 8;
            STEP(0, 0);
            STEP(1, 1);
            STEP(2, 0);
            STEP(3, 1);
        }
        WAIT_VM0;  // next-chunk staging (issued a whole chunk ago) has landed

        if (lane < 32) {  // dump chunk outputs: lane = local t, 4 rows as float4
            float4 t4o = *(const float4*)&Ol[lane][0];
            *(float4*)(out + ((size_t)(j * CH + lane) * BATCH + b) * NDIM + g * 4) = t4o;
        }

        if (j + 1 < T_STEPS / CH) {  // refill slot pipeline from next buffer
            const float* Kn = &Kl[nb][0][0] + c4;
            const float* Qn = &Ql[nb][0][0] + c4;
#pragma unroll
            for (int u = 0; u < 2; ++u) {
                f32x4 kk_ = *(const f32x4*)(Kn + u * 64);
                f32x4 qq_ = *(const f32x4*)(Qn + u * 64);
                k01[u] = kk_.lo; k23[u] = kk_.hi;
                q01[u] = qq_.lo; q23[u] = qq_.hi;
                va[u] = *(const f32x2*)&VAl[nb][u][r * 2];
                kqv[u] = KQl[nb][u];
            }
        }
    }
#undef STEP

    float* so_ = Sout + ((size_t)b * NDIM + i) * NDIM + c4;
    *(float4*)so_ = float4{s01.x, s01.y, s23.x, s23.y};
}

extern "C" void kernel_launch(void* const* d_in, const int* in_sizes, int n_in,
                              void* d_out, int out_size, void* d_ws, size_t ws_size,
                              hipStream_t stream) {
    const float* x  = (const float*)d_in[0];
    const float* S0 = (const float*)d_in[1];
    const float* Wk = (const float*)d_in[2];
    const float* Wv = (const float*)d_in[3];
    const float* Wq = (const float*)d_in[4];
    const float* Wa = (const float*)d_in[5];
    const float* da = (const float*)d_in[6];
    const float* ba = (const float*)d_in[7];

    float* out = (float*)d_out;
    float* Sout = out + (size_t)T_STEPS * BATCH * NDIM;

    const size_t per = (size_t)M_TOTAL * NDIM;
    float* Kp  = (float*)d_ws;           // per floats
    float* Qp  = Kp + per;               // per
    float* VAi = Qp + per;               // 2*per (v,a interleaved per row)
    float* kq  = VAi + 2 * per;          // M_TOTAL
    unsigned short* Wb = (unsigned short*)(kq + M_TOTAL);  // 512 KB bf16

    pack_w<<<dim3(256), dim3(256), 0, stream>>>(Wk, Wq, Wv, Wa, Wb);
    proj_kernel<<<dim3(M_TOTAL / 128, 2), dim3(256), 0, stream>>>(x, Wb, ba, Kp, Qp, VAi);
    kq_kernel<<<dim3(M_TOTAL / 16), dim3(256), 0, stream>>>(Kp, Qp, kq);
    recur_kernel<<<dim3(16, BATCH), dim3(64), 0, stream>>>(Kp, Qp, VAi, kq, S0, da, out, Sout);
    silu_kernel<<<dim3((T_STEPS * BATCH * NDIM) / (256 * 4)), dim3(256), 0, stream>>>(out);
}